// Round 2
// baseline (370.230 us; speedup 1.0000x reference)
//
#include <hip/hip_runtime.h>
#include <math.h>

#define NB 32
#define NP 8732
#define NC 81
#define NM 20
#define CHUNKS 35          // ceil(NP/256)
#define CE_CH (NP / 4)     // 2183 rows-of-4 per image

typedef unsigned long long ull;

// ws byte layout:
//  [0)     acc float[4]: 0=loc_sum 1=conf_pos 2=conf_neg (3 unused)
//  [64)    nposarr int[NB]
//  [256)   bestkey ull[NB*NM]
//  [8192)  ovArr float[NB*NP]
//  [8192+NB*NP*4)          objArr uchar[NB*NP]
//  [8192+NB*NP*5 (aligned)] neg float[NB*NP]

__global__ __launch_bounds__(1024) void init_kernel(unsigned* ws) {
    for (int i = threadIdx.x; i < 2048; i += 1024) ws[i] = 0u;  // zero first 8 KB
}

// ---------------- K1: per-prior match, one thread per prior ----------------
__global__ __launch_bounds__(256)
void match1_kernel(const float* __restrict__ boxes,
                   const float* __restrict__ priors,
                   ull*   __restrict__ bestkey,
                   float* __restrict__ ovArr,
                   unsigned char* __restrict__ objArr)
{
    const int b = blockIdx.x / CHUNKS;
    const int chunk = blockIdx.x % CHUNKS;
    const int tid = threadIdx.x;
    const int p = chunk * 256 + tid;
    const bool valid = p < NP;

    __shared__ float bxs[NM][4];
    __shared__ float areaA[NM];
    __shared__ ull   redk[4][NM];

    if (tid < NM * 4) ((float*)bxs)[tid] = boxes[b * NM * 4 + tid];
    __syncthreads();
    if (tid < NM) areaA[tid] = (bxs[tid][2] - bxs[tid][0]) * (bxs[tid][3] - bxs[tid][1]);
    __syncthreads();

    const int lane = tid & 63, wid = tid >> 6;
    float4 pc = reinterpret_cast<const float4*>(priors)[valid ? p : 0];
    const float px1 = pc.x - pc.z * 0.5f;
    const float py1 = pc.y - pc.w * 0.5f;
    const float px2 = pc.x + pc.z * 0.5f;
    const float py2 = pc.y + pc.w * 0.5f;
    const float pa  = (px2 - px1) * (py2 - py1);

    float bov = -1.f; int bm = 0;
#pragma unroll
    for (int m = 0; m < NM; m++) {
        float ix1 = fmaxf(bxs[m][0], px1);
        float iy1 = fmaxf(bxs[m][1], py1);
        float ix2 = fminf(bxs[m][2], px2);
        float iy2 = fminf(bxs[m][3], py2);
        float iw = fmaxf(ix2 - ix1, 0.f);
        float ih = fmaxf(iy2 - iy1, 0.f);
        float inter = iw * ih;
        float iou = inter / (areaA[m] + pa - inter);
        if (iou > bov) { bov = iou; bm = m; }   // first-max over m
        // per-object argmax over p: pack (iou, smallest-p-wins)
        ull key = valid ? ((((ull)__float_as_uint(iou)) << 32) | (unsigned)(~(unsigned)p)) : 0ull;
#pragma unroll
        for (int off = 32; off; off >>= 1) {
            ull ko = __shfl_down(key, off);
            if (ko > key) key = ko;
        }
        if (lane == 0) redk[wid][m] = key;
    }
    __syncthreads();
    if (tid < NM) {
        ull k = redk[0][tid];
        if (redk[1][tid] > k) k = redk[1][tid];
        if (redk[2][tid] > k) k = redk[2][tid];
        if (redk[3][tid] > k) k = redk[3][tid];
        atomicMax(&bestkey[b * NM + tid], k);
    }
    if (valid) {
        ovArr[(size_t)b * NP + p] = bov;
        objArr[(size_t)b * NP + p] = (unsigned char)bm;
    }
}

// ---------------- K2: force-assign (last-write-wins, parallel) ----------------
__global__ __launch_bounds__(64)
void force_kernel(const ull* __restrict__ bestkey,
                  float* __restrict__ ovArr,
                  unsigned char* __restrict__ objArr)
{
    const int b = blockIdx.x;
    const int lane = threadIdx.x;
    __shared__ int pps[NM];
    if (lane < NM)
        pps[lane] = (int)(~(unsigned)(bestkey[b * NM + lane] & 0xFFFFFFFFull));
    __syncthreads();
    if (lane < NM) {
        int pp = pps[lane];
        bool win = true;
        for (int m2 = lane + 1; m2 < NM; m2++)
            if (pps[m2] == pp) win = false;   // a later m overwrites -> it wins
        if (win) {
            ovArr[(size_t)b * NP + pp] = 1.0f;
            objArr[(size_t)b * NP + pp] = (unsigned char)lane;
        }
    }
}

// ---------------- K3: fused label + CE + loc loss, one wave per row ----------------
__global__ __launch_bounds__(256)
void ce_kernel(const float* __restrict__ scores,
               const float* __restrict__ plocs,
               const float* __restrict__ boxes,
               const int*   __restrict__ labels,
               const float* __restrict__ priors,
               const float* __restrict__ ovArr,
               const unsigned char* __restrict__ objArr,
               float* __restrict__ neg,
               float* __restrict__ acc,
               int*   __restrict__ nposarr)
{
    __shared__ float bsum;      // conf_pos partial
    __shared__ float blocsum;   // loc partial
    __shared__ int   bnp;       // n_pos partial
    const int tid = threadIdx.x;
    if (tid == 0) { bsum = 0.f; blocsum = 0.f; bnp = 0; }
    __syncthreads();

    const int b = blockIdx.x / CE_CH;
    const int chunk = blockIdx.x % CE_CH;
    const int wid = tid >> 6, lane = tid & 63;
    const int p = chunk * 4 + wid;
    const long long r = (long long)b * NP + p;
    const float* base = scores + r * NC;

    float v1 = base[lane];
    float v2 = (lane + 64 < NC) ? base[lane + 64] : -INFINITY;
    float mx = fmaxf(v1, v2);
#pragma unroll
    for (int off = 32; off; off >>= 1) mx = fmaxf(mx, __shfl_xor(mx, off));
    float e = expf(v1 - mx) + ((lane + 64 < NC) ? expf(v2 - mx) : 0.f);
#pragma unroll
    for (int off = 32; off; off >>= 1) e += __shfl_xor(e, off);

    if (lane == 0) {
        float ov = ovArr[r];
        int obj = objArr[r];
        int lab = (ov < 0.5f) ? 0 : labels[b * NM + obj];
        float ce = mx + logf(e) - base[lab];
        if (lab > 0) {
            neg[r] = 0.f;
            atomicAdd(&bsum, ce);
            atomicAdd(&bnp, 1);
            // smooth-L1 on this positive prior
            float4 pc = reinterpret_cast<const float4*>(priors)[p];
            const float* bx = boxes + ((size_t)b * NM + obj) * 4;
            float x1 = bx[0], y1 = bx[1], x2 = bx[2], y2 = bx[3];
            float bcx = (x1 + x2) * 0.5f, bcy = (y1 + y2) * 0.5f;
            float bw = x2 - x1, bh = y2 - y1;
            float g0 = (bcx - pc.x) / (pc.z / 10.f);
            float g1 = (bcy - pc.y) / (pc.w / 10.f);
            float g2 = logf(bw / pc.z) * 5.f;
            float g3 = logf(bh / pc.w) * 5.f;
            float4 pl = reinterpret_cast<const float4*>(plocs)[r];
            float s = 0.f, d, ad;
            d = pl.x - g0; ad = fabsf(d); s += (ad < 1.f) ? 0.5f * d * d : ad - 0.5f;
            d = pl.y - g1; ad = fabsf(d); s += (ad < 1.f) ? 0.5f * d * d : ad - 0.5f;
            d = pl.z - g2; ad = fabsf(d); s += (ad < 1.f) ? 0.5f * d * d : ad - 0.5f;
            d = pl.w - g3; ad = fabsf(d); s += (ad < 1.f) ? 0.5f * d * d : ad - 0.5f;
            atomicAdd(&blocsum, s);
        } else {
            neg[r] = ce;
        }
    }
    __syncthreads();
    if (tid == 0 && bnp > 0) {
        atomicAdd(&acc[1], bsum);
        atomicAdd(&acc[0], blocsum);
        atomicAdd(&nposarr[b], bnp);
    }
}

// ---------------- K4: hard-negative mining ----------------
__global__ __launch_bounds__(256)
void mine_kernel(const float* __restrict__ neg,
                 const int*   __restrict__ nposarr,
                 float* __restrict__ acc)
{
    __shared__ float vals[NP];
    __shared__ float fredS[4];
    __shared__ int   iredS[4];
    const int b = blockIdx.x;
    const int tid = threadIdx.x;
    const float* src = neg + (size_t)b * NP;
    for (int p = tid; p < NP; p += 256) vals[p] = src[p];
    int k = nposarr[b] * 3;
    if (k > NP) k = NP;
    __syncthreads();
    const int lane = tid & 63, wid = tid >> 6;

    unsigned lo = 0u, hi = 0x7f7fffffu;
    while (lo < hi) {
        unsigned mid = lo + ((hi - lo + 1u) >> 1);
        float t = __uint_as_float(mid);
        int cnt = 0;
        for (int p = tid; p < NP; p += 256) cnt += (vals[p] >= t) ? 1 : 0;
#pragma unroll
        for (int off = 32; off; off >>= 1) cnt += __shfl_xor(cnt, off);
        if (lane == 0) iredS[wid] = cnt;
        __syncthreads();
        int total = iredS[0] + iredS[1] + iredS[2] + iredS[3];
        __syncthreads();
        if (total >= k) lo = mid; else hi = mid - 1u;
    }
    float t = __uint_as_float(lo);
    float s = 0.f; int cg = 0;
    for (int p = tid; p < NP; p += 256) {
        float v = vals[p];
        if (v > t) { s += v; cg++; }
    }
#pragma unroll
    for (int off = 32; off; off >>= 1) { s += __shfl_down(s, off); cg += __shfl_down(cg, off); }
    if (lane == 0) { fredS[wid] = s; iredS[wid] = cg; }
    __syncthreads();
    if (tid == 0) {
        float sum = fredS[0] + fredS[1] + fredS[2] + fredS[3];
        int cG = iredS[0] + iredS[1] + iredS[2] + iredS[3];
        atomicAdd(&acc[2], sum + (float)(k - cG) * t);
    }
}

// ---------------- finalize ----------------
__global__ __launch_bounds__(64)
void fin_kernel(const float* __restrict__ acc,
                const int* __restrict__ nposarr,
                float* __restrict__ out)
{
    int lane = threadIdx.x;
    int n = (lane < NB) ? nposarr[lane] : 0;
#pragma unroll
    for (int off = 32; off; off >>= 1) n += __shfl_down(n, off);
    if (lane == 0) {
        float nt = (float)n;
        out[0] = (acc[2] + acc[1]) / nt;   // conf_loss
        out[1] = acc[0] / (nt * 4.f);      // loc_loss (ALPHA=1)
    }
}

extern "C" void kernel_launch(void* const* d_in, const int* in_sizes, int n_in,
                              void* d_out, int out_size, void* d_ws, size_t ws_size,
                              hipStream_t stream)
{
    const float* plocs  = (const float*)d_in[0];
    const float* scores = (const float*)d_in[1];
    const float* boxes  = (const float*)d_in[2];
    const int*   labels = (const int*)d_in[3];
    const float* priors = (const float*)d_in[4];
    float* out = (float*)d_out;

    char* base = (char*)d_ws;
    float* acc     = (float*)base;
    int*   nposarr = (int*)(base + 64);
    ull*   bestkey = (ull*)(base + 256);
    float* ovArr   = (float*)(base + 8192);
    unsigned char* objArr = (unsigned char*)(base + 8192 + (size_t)NB * NP * 4);
    size_t negOff = 8192 + (size_t)NB * NP * 5;
    negOff = (negOff + 255) & ~(size_t)255;
    float* neg = (float*)(base + negOff);

    hipLaunchKernelGGL(init_kernel, dim3(1), dim3(1024), 0, stream, (unsigned*)d_ws);
    hipLaunchKernelGGL(match1_kernel, dim3(NB * CHUNKS), dim3(256), 0, stream,
                       boxes, priors, bestkey, ovArr, objArr);
    hipLaunchKernelGGL(force_kernel, dim3(NB), dim3(64), 0, stream,
                       bestkey, ovArr, objArr);
    hipLaunchKernelGGL(ce_kernel, dim3(NB * CE_CH), dim3(256), 0, stream,
                       scores, plocs, boxes, labels, priors, ovArr, objArr,
                       neg, acc, nposarr);
    hipLaunchKernelGGL(mine_kernel, dim3(NB), dim3(256), 0, stream, neg, nposarr, acc);
    hipLaunchKernelGGL(fin_kernel, dim3(1), dim3(64), 0, stream, acc, nposarr, out);
}

// Round 3
// 228.959 us; speedup vs baseline: 1.6170x; 1.6170x over previous
//
#include <hip/hip_runtime.h>
#include <math.h>

#define NB 32
#define NP 8732
#define NC 81
#define NM 20
#define CHUNKS 35          // ceil(NP/256) for match
#define CE_BLOCKS 4366     // 279424 / 64 exactly

typedef unsigned long long ull;

// ws byte layout:
//  [0)     acc float[4]: 0=loc_sum 1=conf_pos 2=conf_neg
//  [64)    nposarr int[NB]
//  [256)   bestkey ull[NB*NM]
//  [8192)  ovArr float[NB*NP]
//  [8192+NB*NP*4)           objArr uchar[NB*NP]
//  [aligned after objArr]   neg float[NB*NP]

__global__ __launch_bounds__(1024) void init_kernel(unsigned* ws) {
    for (int i = threadIdx.x; i < 2048; i += 1024) ws[i] = 0u;  // zero first 8 KB
}

// ---------------- K1: per-prior match, one thread per prior ----------------
__global__ __launch_bounds__(256)
void match1_kernel(const float* __restrict__ boxes,
                   const float* __restrict__ priors,
                   ull*   __restrict__ bestkey,
                   float* __restrict__ ovArr,
                   unsigned char* __restrict__ objArr)
{
    const int b = blockIdx.x / CHUNKS;
    const int chunk = blockIdx.x % CHUNKS;
    const int tid = threadIdx.x;
    const int p = chunk * 256 + tid;
    const bool valid = p < NP;

    __shared__ float bxs[NM][4];
    __shared__ float areaA[NM];
    __shared__ ull   redk[4][NM];

    if (tid < NM * 4) ((float*)bxs)[tid] = boxes[b * NM * 4 + tid];
    __syncthreads();
    if (tid < NM) areaA[tid] = (bxs[tid][2] - bxs[tid][0]) * (bxs[tid][3] - bxs[tid][1]);
    __syncthreads();

    const int lane = tid & 63, wid = tid >> 6;
    float4 pc = reinterpret_cast<const float4*>(priors)[valid ? p : 0];
    const float px1 = pc.x - pc.z * 0.5f;
    const float py1 = pc.y - pc.w * 0.5f;
    const float px2 = pc.x + pc.z * 0.5f;
    const float py2 = pc.y + pc.w * 0.5f;
    const float pa  = (px2 - px1) * (py2 - py1);

    float bov = -1.f; int bm = 0;
#pragma unroll
    for (int m = 0; m < NM; m++) {
        float ix1 = fmaxf(bxs[m][0], px1);
        float iy1 = fmaxf(bxs[m][1], py1);
        float ix2 = fminf(bxs[m][2], px2);
        float iy2 = fminf(bxs[m][3], py2);
        float iw = fmaxf(ix2 - ix1, 0.f);
        float ih = fmaxf(iy2 - iy1, 0.f);
        float inter = iw * ih;
        float iou = inter / (areaA[m] + pa - inter);
        if (iou > bov) { bov = iou; bm = m; }   // first-max over m
        ull key = valid ? ((((ull)__float_as_uint(iou)) << 32) | (unsigned)(~(unsigned)p)) : 0ull;
#pragma unroll
        for (int off = 32; off; off >>= 1) {
            ull ko = __shfl_down(key, off);
            if (ko > key) key = ko;
        }
        if (lane == 0) redk[wid][m] = key;
    }
    __syncthreads();
    if (tid < NM) {
        ull k = redk[0][tid];
        if (redk[1][tid] > k) k = redk[1][tid];
        if (redk[2][tid] > k) k = redk[2][tid];
        if (redk[3][tid] > k) k = redk[3][tid];
        atomicMax(&bestkey[b * NM + tid], k);
    }
    if (valid) {
        ovArr[(size_t)b * NP + p] = bov;
        objArr[(size_t)b * NP + p] = (unsigned char)bm;
    }
}

// ---------------- K2: force-assign (last-write-wins, parallel) ----------------
__global__ __launch_bounds__(64)
void force_kernel(const ull* __restrict__ bestkey,
                  float* __restrict__ ovArr,
                  unsigned char* __restrict__ objArr)
{
    const int b = blockIdx.x;
    const int lane = threadIdx.x;
    __shared__ int pps[NM];
    if (lane < NM)
        pps[lane] = (int)(~(unsigned)(bestkey[b * NM + lane] & 0xFFFFFFFFull));
    __syncthreads();
    if (lane < NM) {
        int pp = pps[lane];
        bool win = true;
        for (int m2 = lane + 1; m2 < NM; m2++)
            if (pps[m2] == pp) win = false;
        if (win) {
            ovArr[(size_t)b * NP + pp] = 1.0f;
            objArr[(size_t)b * NP + pp] = (unsigned char)lane;
        }
    }
}

// ---------------- K3: fused CE + labels + loc loss, thread-per-row ----------------
__global__ __launch_bounds__(64)
void ce_kernel(const float* __restrict__ scores,
               const float* __restrict__ plocs,
               const float* __restrict__ boxes,
               const int*   __restrict__ labels,
               const float* __restrict__ priors,
               const float* __restrict__ ovArr,
               const unsigned char* __restrict__ objArr,
               float* __restrict__ neg,
               float* __restrict__ acc,
               int*   __restrict__ nposarr)
{
    __shared__ float lds[64 * NC];   // 20736 B
    __shared__ float bsum, blocsum;
    const int tid = threadIdx.x;
    const int tile = blockIdx.x;
    const int r = tile * 64 + tid;          // < 279424
    const int b = r / NP;
    const int p = r - b * NP;

    // early independent loads (hide under staging)
    float ov = ovArr[r];
    int obj = objArr[r];

    // stage 64 rows (5184 floats = 1296 float4), fully coalesced
    const float4* src = reinterpret_cast<const float4*>(scores + (size_t)tile * 64 * NC);
    float4* dst = reinterpret_cast<float4*>(lds);
#pragma unroll
    for (int i = 0; i < 20; i++) dst[tid + i * 64] = src[tid + i * 64];
    if (tid < 16) dst[1280 + tid] = src[1280 + tid];
    if (tid == 0) { bsum = 0.f; blocsum = 0.f; }

    int lab = (ov < 0.5f) ? 0 : labels[b * NM + obj];
    __syncthreads();

    const float* row = lds + tid * NC;      // stride 81 dwords: conflict-free
    float m0 = -1e30f, m1 = -1e30f, m2 = -1e30f, m3 = -1e30f;
#pragma unroll
    for (int c = 0; c < 80; c += 4) {
        m0 = fmaxf(m0, row[c]);
        m1 = fmaxf(m1, row[c + 1]);
        m2 = fmaxf(m2, row[c + 2]);
        m3 = fmaxf(m3, row[c + 3]);
    }
    float m = fmaxf(fmaxf(fmaxf(m0, m1), fmaxf(m2, m3)), row[80]);
    float s0 = 0.f, s1 = 0.f, s2 = 0.f, s3 = 0.f;
#pragma unroll
    for (int c = 0; c < 80; c += 4) {
        s0 += expf(row[c] - m);
        s1 += expf(row[c + 1] - m);
        s2 += expf(row[c + 2] - m);
        s3 += expf(row[c + 3] - m);
    }
    float s = (s0 + s1) + (s2 + s3) + expf(row[80] - m);
    float ce = m + logf(s) - row[lab];

    if (lab > 0) {
        neg[r] = 0.f;
        atomicAdd(&bsum, ce);
        atomicAdd(&nposarr[b], 1);
        float4 pc = reinterpret_cast<const float4*>(priors)[p];
        const float* bx = boxes + ((size_t)b * NM + obj) * 4;
        float x1 = bx[0], y1 = bx[1], x2 = bx[2], y2 = bx[3];
        float bcx = (x1 + x2) * 0.5f, bcy = (y1 + y2) * 0.5f;
        float bw = x2 - x1, bh = y2 - y1;
        float g0 = (bcx - pc.x) / (pc.z / 10.f);
        float g1 = (bcy - pc.y) / (pc.w / 10.f);
        float g2 = logf(bw / pc.z) * 5.f;
        float g3 = logf(bh / pc.w) * 5.f;
        float4 pl = reinterpret_cast<const float4*>(plocs)[r];
        float t = 0.f, d, ad;
        d = pl.x - g0; ad = fabsf(d); t += (ad < 1.f) ? 0.5f * d * d : ad - 0.5f;
        d = pl.y - g1; ad = fabsf(d); t += (ad < 1.f) ? 0.5f * d * d : ad - 0.5f;
        d = pl.z - g2; ad = fabsf(d); t += (ad < 1.f) ? 0.5f * d * d : ad - 0.5f;
        d = pl.w - g3; ad = fabsf(d); t += (ad < 1.f) ? 0.5f * d * d : ad - 0.5f;
        atomicAdd(&blocsum, t);
    } else {
        neg[r] = ce;
    }
    __syncthreads();
    if (tid == 0) {
        if (bsum != 0.f)    atomicAdd(&acc[1], bsum);
        if (blocsum != 0.f) atomicAdd(&acc[0], blocsum);
    }
}

// ---------------- K4: hard-negative mining (quad-probe bisection) ----------------
__global__ __launch_bounds__(1024)
void mine_kernel(const float* __restrict__ neg,
                 const int*   __restrict__ nposarr,
                 float* __restrict__ acc)
{
    __shared__ float vals[NP];
    __shared__ ull   redU[16];
    __shared__ float redF[16];
    __shared__ int   redI[16];
    const int b = blockIdx.x;
    const int tid = threadIdx.x;
    const float* src = neg + (size_t)b * NP;
    for (int p = tid; p < NP; p += 1024) vals[p] = src[p];
    int k = nposarr[b] * 3;
    if (k > NP) k = NP;
    __syncthreads();
    const int lane = tid & 63, wid = tid >> 6;

    unsigned lo = 0u, hi = 0x7f7fffffu;
    while (lo < hi) {
        if (hi - lo >= 3u) {
            unsigned w4 = (hi - lo + 1u) >> 2;
            unsigned u1 = lo + w4, u2 = lo + 2u * w4, u3 = lo + 3u * w4;
            float t1 = __uint_as_float(u1), t2 = __uint_as_float(u2), t3 = __uint_as_float(u3);
            ull c = 0ull;
            for (int p = tid; p < NP; p += 1024) {
                float v = vals[p];
                c += (v >= t1 ? 1ull : 0ull)
                   + (v >= t2 ? (1ull << 21) : 0ull)
                   + (v >= t3 ? (1ull << 42) : 0ull);
            }
#pragma unroll
            for (int off = 32; off; off >>= 1) c += __shfl_xor(c, off);
            if (lane == 0) redU[wid] = c;
            __syncthreads();
            ull tot = 0ull;
#pragma unroll
            for (int w = 0; w < 16; w++) tot += redU[w];
            __syncthreads();
            int c1 = (int)(tot & 0x1FFFFFull);
            int c2 = (int)((tot >> 21) & 0x1FFFFFull);
            int c3 = (int)(tot >> 42);
            if      (c3 >= k) lo = u3;
            else if (c2 >= k) { lo = u2; hi = u3 - 1u; }
            else if (c1 >= k) { lo = u1; hi = u2 - 1u; }
            else              hi = u1 - 1u;
        } else {
            unsigned mid = lo + ((hi - lo + 1u) >> 1);
            float t = __uint_as_float(mid);
            int cnt = 0;
            for (int p = tid; p < NP; p += 1024) cnt += (vals[p] >= t) ? 1 : 0;
#pragma unroll
            for (int off = 32; off; off >>= 1) cnt += __shfl_xor(cnt, off);
            if (lane == 0) redI[wid] = cnt;
            __syncthreads();
            int tot = 0;
#pragma unroll
            for (int w = 0; w < 16; w++) tot += redI[w];
            __syncthreads();
            if (tot >= k) lo = mid; else hi = mid - 1u;
        }
    }
    float t = __uint_as_float(lo);   // exact k-th largest
    float s = 0.f; int cg = 0;
    for (int p = tid; p < NP; p += 1024) {
        float v = vals[p];
        if (v > t) { s += v; cg++; }
    }
#pragma unroll
    for (int off = 32; off; off >>= 1) { s += __shfl_down(s, off); cg += __shfl_down(cg, off); }
    if (lane == 0) { redF[wid] = s; redI[wid] = cg; }
    __syncthreads();
    if (tid == 0) {
        float sum = 0.f; int cG = 0;
#pragma unroll
        for (int w = 0; w < 16; w++) { sum += redF[w]; cG += redI[w]; }
        atomicAdd(&acc[2], sum + (float)(k - cG) * t);
    }
}

// ---------------- finalize ----------------
__global__ __launch_bounds__(64)
void fin_kernel(const float* __restrict__ acc,
                const int* __restrict__ nposarr,
                float* __restrict__ out)
{
    int lane = threadIdx.x;
    int n = (lane < NB) ? nposarr[lane] : 0;
#pragma unroll
    for (int off = 32; off; off >>= 1) n += __shfl_down(n, off);
    if (lane == 0) {
        float nt = (float)n;
        out[0] = (acc[2] + acc[1]) / nt;   // conf_loss
        out[1] = acc[0] / (nt * 4.f);      // loc_loss (ALPHA=1)
    }
}

extern "C" void kernel_launch(void* const* d_in, const int* in_sizes, int n_in,
                              void* d_out, int out_size, void* d_ws, size_t ws_size,
                              hipStream_t stream)
{
    const float* plocs  = (const float*)d_in[0];
    const float* scores = (const float*)d_in[1];
    const float* boxes  = (const float*)d_in[2];
    const int*   labels = (const int*)d_in[3];
    const float* priors = (const float*)d_in[4];
    float* out = (float*)d_out;

    char* base = (char*)d_ws;
    float* acc     = (float*)base;
    int*   nposarr = (int*)(base + 64);
    ull*   bestkey = (ull*)(base + 256);
    float* ovArr   = (float*)(base + 8192);
    unsigned char* objArr = (unsigned char*)(base + 8192 + (size_t)NB * NP * 4);
    size_t negOff = 8192 + (size_t)NB * NP * 5;
    negOff = (negOff + 255) & ~(size_t)255;
    float* neg = (float*)(base + negOff);

    hipLaunchKernelGGL(init_kernel, dim3(1), dim3(1024), 0, stream, (unsigned*)d_ws);
    hipLaunchKernelGGL(match1_kernel, dim3(NB * CHUNKS), dim3(256), 0, stream,
                       boxes, priors, bestkey, ovArr, objArr);
    hipLaunchKernelGGL(force_kernel, dim3(NB), dim3(64), 0, stream,
                       bestkey, ovArr, objArr);
    hipLaunchKernelGGL(ce_kernel, dim3(CE_BLOCKS), dim3(64), 0, stream,
                       scores, plocs, boxes, labels, priors, ovArr, objArr,
                       neg, acc, nposarr);
    hipLaunchKernelGGL(mine_kernel, dim3(NB), dim3(1024), 0, stream, neg, nposarr, acc);
    hipLaunchKernelGGL(fin_kernel, dim3(1), dim3(64), 0, stream, acc, nposarr, out);
}

// Round 4
// 104.722 us; speedup vs baseline: 3.5354x; 2.1864x over previous
//
#include <hip/hip_runtime.h>
#include <math.h>

#define NB 32
#define NP 8732
#define NC 81
#define NM 20
#define CHUNKS 35          // ceil(NP/256) for match
#define NROWS (NB * NP)    // 279424
#define CE_BLOCKS ((NROWS + 255) / 256)   // 1092

typedef unsigned long long ull;

// ws byte layout:
//  [0)     acc float[4]: 0=loc_sum 1=conf_pos 2=conf_neg
//  [64)    nposarr int[NB]
//  [256)   bestkey ull[NB*NM]
//  [8192)  ovArr float[NB*NP]
//  [8192+NB*NP*4)           objArr uchar[NB*NP]
//  [aligned after objArr]   neg float[NB*NP]

__global__ __launch_bounds__(1024) void init_kernel(unsigned* ws) {
    for (int i = threadIdx.x; i < 2048; i += 1024) ws[i] = 0u;  // zero first 8 KB
}

// ---------------- K1: per-prior match, one thread per prior ----------------
__global__ __launch_bounds__(256)
void match1_kernel(const float* __restrict__ boxes,
                   const float* __restrict__ priors,
                   ull*   __restrict__ bestkey,
                   float* __restrict__ ovArr,
                   unsigned char* __restrict__ objArr)
{
    const int b = blockIdx.x / CHUNKS;
    const int chunk = blockIdx.x % CHUNKS;
    const int tid = threadIdx.x;
    const int p = chunk * 256 + tid;
    const bool valid = p < NP;

    __shared__ float bxs[NM][4];
    __shared__ float areaA[NM];
    __shared__ ull   redk[4][NM];

    if (tid < NM * 4) ((float*)bxs)[tid] = boxes[b * NM * 4 + tid];
    __syncthreads();
    if (tid < NM) areaA[tid] = (bxs[tid][2] - bxs[tid][0]) * (bxs[tid][3] - bxs[tid][1]);
    __syncthreads();

    const int lane = tid & 63, wid = tid >> 6;
    float4 pc = reinterpret_cast<const float4*>(priors)[valid ? p : 0];
    const float px1 = pc.x - pc.z * 0.5f;
    const float py1 = pc.y - pc.w * 0.5f;
    const float px2 = pc.x + pc.z * 0.5f;
    const float py2 = pc.y + pc.w * 0.5f;
    const float pa  = (px2 - px1) * (py2 - py1);

    float bov = -1.f; int bm = 0;
#pragma unroll
    for (int m = 0; m < NM; m++) {
        float ix1 = fmaxf(bxs[m][0], px1);
        float iy1 = fmaxf(bxs[m][1], py1);
        float ix2 = fminf(bxs[m][2], px2);
        float iy2 = fminf(bxs[m][3], py2);
        float iw = fmaxf(ix2 - ix1, 0.f);
        float ih = fmaxf(iy2 - iy1, 0.f);
        float inter = iw * ih;
        float iou = inter / (areaA[m] + pa - inter);
        if (iou > bov) { bov = iou; bm = m; }   // first-max over m
        ull key = valid ? ((((ull)__float_as_uint(iou)) << 32) | (unsigned)(~(unsigned)p)) : 0ull;
#pragma unroll
        for (int off = 32; off; off >>= 1) {
            ull ko = __shfl_down(key, off);
            if (ko > key) key = ko;
        }
        if (lane == 0) redk[wid][m] = key;
    }
    __syncthreads();
    if (tid < NM) {
        ull k = redk[0][tid];
        if (redk[1][tid] > k) k = redk[1][tid];
        if (redk[2][tid] > k) k = redk[2][tid];
        if (redk[3][tid] > k) k = redk[3][tid];
        atomicMax(&bestkey[b * NM + tid], k);
    }
    if (valid) {
        ovArr[(size_t)b * NP + p] = bov;
        objArr[(size_t)b * NP + p] = (unsigned char)bm;
    }
}

// ---------------- K2: force-assign (last-write-wins, parallel) ----------------
__global__ __launch_bounds__(64)
void force_kernel(const ull* __restrict__ bestkey,
                  float* __restrict__ ovArr,
                  unsigned char* __restrict__ objArr)
{
    const int b = blockIdx.x;
    const int lane = threadIdx.x;
    __shared__ int pps[NM];
    if (lane < NM)
        pps[lane] = (int)(~(unsigned)(bestkey[b * NM + lane] & 0xFFFFFFFFull));
    __syncthreads();
    if (lane < NM) {
        int pp = pps[lane];
        bool win = true;
        for (int m2 = lane + 1; m2 < NM; m2++)
            if (pps[m2] == pp) win = false;
        if (win) {
            ovArr[(size_t)b * NP + pp] = 1.0f;
            objArr[(size_t)b * NP + pp] = (unsigned char)lane;
        }
    }
}

// ---------------- K3: fused CE + labels + loc loss, thread-per-row, row in regs ----------------
__global__ __launch_bounds__(256, 4)
void ce_kernel(const float* __restrict__ scores,
               const float* __restrict__ plocs,
               const float* __restrict__ boxes,
               const int*   __restrict__ labels,
               const float* __restrict__ priors,
               const float* __restrict__ ovArr,
               const unsigned char* __restrict__ objArr,
               float* __restrict__ neg,
               float* __restrict__ acc,
               int*   __restrict__ nposarr)
{
    __shared__ float bsum, blocsum;
    __shared__ int bnp[2];
    const int tid = threadIdx.x;
    if (tid < 2) bnp[tid] = 0;
    if (tid == 0) { bsum = 0.f; blocsum = 0.f; }
    __syncthreads();

    const int r = blockIdx.x * 256 + tid;
    const int bfirst = (blockIdx.x * 256) / NP;
    const bool valid = r < NROWS;
    const int rr = valid ? r : 0;
    const int b = rr / NP;
    const int p = rr - b * NP;

    float ov = ovArr[rr];
    int obj = objArr[rr];
    int lab = (ov < 0.5f) ? 0 : labels[b * NM + obj];

    const float* row = scores + (size_t)rr * NC;
    float m0 = -1e30f, m1 = -1e30f, m2 = -1e30f, m3 = -1e30f;
    float labval = 0.f;
    float v[NC];
#pragma unroll
    for (int c = 0; c < NC; c++) v[c] = row[c];
#pragma unroll
    for (int c = 0; c < 80; c += 4) {
        m0 = fmaxf(m0, v[c]);
        m1 = fmaxf(m1, v[c + 1]);
        m2 = fmaxf(m2, v[c + 2]);
        m3 = fmaxf(m3, v[c + 3]);
    }
#pragma unroll
    for (int c = 0; c < NC; c++) if (c == lab) labval = v[c];
    float m = fmaxf(fmaxf(fmaxf(m0, m1), fmaxf(m2, m3)), v[80]);
    float s0 = 0.f, s1 = 0.f, s2 = 0.f, s3 = 0.f;
#pragma unroll
    for (int c = 0; c < 80; c += 4) {
        s0 += __expf(v[c] - m) ;
        s1 += __expf(v[c + 1] - m);
        s2 += __expf(v[c + 2] - m);
        s3 += __expf(v[c + 3] - m);
    }
    float s = (s0 + s1) + (s2 + s3) + __expf(v[80] - m);
    float ce = m + logf(s) - labval;

    if (valid) {
        if (lab > 0) {
            neg[r] = 0.f;
            atomicAdd(&bsum, ce);
            atomicAdd(&bnp[b - bfirst], 1);
            float4 pc = reinterpret_cast<const float4*>(priors)[p];
            const float* bx = boxes + ((size_t)b * NM + obj) * 4;
            float x1 = bx[0], y1 = bx[1], x2 = bx[2], y2 = bx[3];
            float bcx = (x1 + x2) * 0.5f, bcy = (y1 + y2) * 0.5f;
            float bw = x2 - x1, bh = y2 - y1;
            float g0 = (bcx - pc.x) / (pc.z / 10.f);
            float g1 = (bcy - pc.y) / (pc.w / 10.f);
            float g2 = logf(bw / pc.z) * 5.f;
            float g3 = logf(bh / pc.w) * 5.f;
            float4 pl = reinterpret_cast<const float4*>(plocs)[rr];
            float t = 0.f, d, ad;
            d = pl.x - g0; ad = fabsf(d); t += (ad < 1.f) ? 0.5f * d * d : ad - 0.5f;
            d = pl.y - g1; ad = fabsf(d); t += (ad < 1.f) ? 0.5f * d * d : ad - 0.5f;
            d = pl.z - g2; ad = fabsf(d); t += (ad < 1.f) ? 0.5f * d * d : ad - 0.5f;
            d = pl.w - g3; ad = fabsf(d); t += (ad < 1.f) ? 0.5f * d * d : ad - 0.5f;
            atomicAdd(&blocsum, t);
        } else {
            neg[r] = ce;
        }
    }
    __syncthreads();
    if (tid == 0) {
        if (bsum != 0.f)    atomicAdd(&acc[1], bsum);
        if (blocsum != 0.f) atomicAdd(&acc[0], blocsum);
        if (bnp[0] > 0)     atomicAdd(&nposarr[bfirst], bnp[0]);
    }
    if (tid == 1 && bnp[1] > 0) atomicAdd(&nposarr[bfirst + 1], bnp[1]);
}

// ---------------- K4: hard-negative mining (quad-probe bisection) ----------------
__global__ __launch_bounds__(1024)
void mine_kernel(const float* __restrict__ neg,
                 const int*   __restrict__ nposarr,
                 float* __restrict__ acc)
{
    __shared__ float vals[NP];
    __shared__ ull   redU[16];
    __shared__ float redF[16];
    __shared__ int   redI[16];
    const int b = blockIdx.x;
    const int tid = threadIdx.x;
    const float* src = neg + (size_t)b * NP;
    for (int p = tid; p < NP; p += 1024) vals[p] = src[p];
    int k = nposarr[b] * 3;
    if (k > NP) k = NP;
    __syncthreads();
    const int lane = tid & 63, wid = tid >> 6;

    unsigned lo = 0u, hi = 0x7f7fffffu;
    while (lo < hi) {
        if (hi - lo >= 3u) {
            unsigned w4 = (hi - lo + 1u) >> 2;
            unsigned u1 = lo + w4, u2 = lo + 2u * w4, u3 = lo + 3u * w4;
            float t1 = __uint_as_float(u1), t2 = __uint_as_float(u2), t3 = __uint_as_float(u3);
            ull c = 0ull;
            for (int p = tid; p < NP; p += 1024) {
                float v = vals[p];
                c += (v >= t1 ? 1ull : 0ull)
                   + (v >= t2 ? (1ull << 21) : 0ull)
                   + (v >= t3 ? (1ull << 42) : 0ull);
            }
#pragma unroll
            for (int off = 32; off; off >>= 1) c += __shfl_xor(c, off);
            if (lane == 0) redU[wid] = c;
            __syncthreads();
            ull tot = 0ull;
#pragma unroll
            for (int w = 0; w < 16; w++) tot += redU[w];
            __syncthreads();
            int c1 = (int)(tot & 0x1FFFFFull);
            int c2 = (int)((tot >> 21) & 0x1FFFFFull);
            int c3 = (int)(tot >> 42);
            if      (c3 >= k) lo = u3;
            else if (c2 >= k) { lo = u2; hi = u3 - 1u; }
            else if (c1 >= k) { lo = u1; hi = u2 - 1u; }
            else              hi = u1 - 1u;
        } else {
            unsigned mid = lo + ((hi - lo + 1u) >> 1);
            float t = __uint_as_float(mid);
            int cnt = 0;
            for (int p = tid; p < NP; p += 1024) cnt += (vals[p] >= t) ? 1 : 0;
#pragma unroll
            for (int off = 32; off; off >>= 1) cnt += __shfl_xor(cnt, off);
            if (lane == 0) redI[wid] = cnt;
            __syncthreads();
            int tot = 0;
#pragma unroll
            for (int w = 0; w < 16; w++) tot += redI[w];
            __syncthreads();
            if (tot >= k) lo = mid; else hi = mid - 1u;
        }
    }
    float t = __uint_as_float(lo);   // exact k-th largest
    float s = 0.f; int cg = 0;
    for (int p = tid; p < NP; p += 1024) {
        float v = vals[p];
        if (v > t) { s += v; cg++; }
    }
#pragma unroll
    for (int off = 32; off; off >>= 1) { s += __shfl_down(s, off); cg += __shfl_down(cg, off); }
    if (lane == 0) { redF[wid] = s; redI[wid] = cg; }
    __syncthreads();
    if (tid == 0) {
        float sum = 0.f; int cG = 0;
#pragma unroll
        for (int w = 0; w < 16; w++) { sum += redF[w]; cG += redI[w]; }
        atomicAdd(&acc[2], sum + (float)(k - cG) * t);
    }
}

// ---------------- finalize ----------------
__global__ __launch_bounds__(64)
void fin_kernel(const float* __restrict__ acc,
                const int* __restrict__ nposarr,
                float* __restrict__ out)
{
    int lane = threadIdx.x;
    int n = (lane < NB) ? nposarr[lane] : 0;
#pragma unroll
    for (int off = 32; off; off >>= 1) n += __shfl_down(n, off);
    if (lane == 0) {
        float nt = (float)n;
        out[0] = (acc[2] + acc[1]) / nt;   // conf_loss
        out[1] = acc[0] / (nt * 4.f);      // loc_loss (ALPHA=1)
    }
}

extern "C" void kernel_launch(void* const* d_in, const int* in_sizes, int n_in,
                              void* d_out, int out_size, void* d_ws, size_t ws_size,
                              hipStream_t stream)
{
    const float* plocs  = (const float*)d_in[0];
    const float* scores = (const float*)d_in[1];
    const float* boxes  = (const float*)d_in[2];
    const int*   labels = (const int*)d_in[3];
    const float* priors = (const float*)d_in[4];
    float* out = (float*)d_out;

    char* base = (char*)d_ws;
    float* acc     = (float*)base;
    int*   nposarr = (int*)(base + 64);
    ull*   bestkey = (ull*)(base + 256);
    float* ovArr   = (float*)(base + 8192);
    unsigned char* objArr = (unsigned char*)(base + 8192 + (size_t)NB * NP * 4);
    size_t negOff = 8192 + (size_t)NB * NP * 5;
    negOff = (negOff + 255) & ~(size_t)255;
    float* neg = (float*)(base + negOff);

    hipLaunchKernelGGL(init_kernel, dim3(1), dim3(1024), 0, stream, (unsigned*)d_ws);
    hipLaunchKernelGGL(match1_kernel, dim3(NB * CHUNKS), dim3(256), 0, stream,
                       boxes, priors, bestkey, ovArr, objArr);
    hipLaunchKernelGGL(force_kernel, dim3(NB), dim3(64), 0, stream,
                       bestkey, ovArr, objArr);
    hipLaunchKernelGGL(ce_kernel, dim3(CE_BLOCKS), dim3(256), 0, stream,
                       scores, plocs, boxes, labels, priors, ovArr, objArr,
                       neg, acc, nposarr);
    hipLaunchKernelGGL(mine_kernel, dim3(NB), dim3(1024), 0, stream, neg, nposarr, acc);
    hipLaunchKernelGGL(fin_kernel, dim3(1), dim3(64), 0, stream, acc, nposarr, out);
}